// Round 4
// baseline (426.119 us; speedup 1.0000x reference)
//
#include <hip/hip_runtime.h>

// Product quantizer: N=16384, D=1024, M=64 subspaces, K=256 codes, d=16.
//
// Phase 1 (pq_main): split-bf16 MFMA scores s = x·c - 0.5||c||^2 (argmax == argmin
//   dist; 3 products ch·xh + cl·xh + ch·xl, |err| ~ 5e-4). Emits a 1-BYTE code per
//   (n,m), stored in the first 64 bytes of out row n (overwritten later by phase 2).
//   Top-2 gap < MARGIN -> flag list in d_ws.
// Refine (pq_refine): exact f64 re-decision for flagged (n,m), first-min tie-break;
//   rewrites the idx byte.
// Phase 2 (pq_gather): reads idx bytes, gathers codewords (codebooks are L2-hot),
//   writes full 4 KB output rows, perfectly coalesced.

#define NROWS  16384
#define DIMS   1024
#define MSUB   64
#define KCODE  256
#define DSUB   16

static constexpr float MARGIN = 0.03f;

typedef __attribute__((ext_vector_type(4))) short s16x4;
typedef __attribute__((ext_vector_type(4))) float f32x4;

static __device__ __forceinline__ short f2bf(float f) {
    unsigned u = __float_as_uint(f);
    u += 0x7fffu + ((u >> 16) & 1u);          // RNE to bf16
    return (short)(u >> 16);
}
static __device__ __forceinline__ float bf2f(short h) {
    return __uint_as_float(((unsigned)(unsigned short)h) << 16);
}

static __device__ __forceinline__ f32x4 mfma16(s16x4 a, s16x4 b, f32x4 c) {
#if __has_builtin(__builtin_amdgcn_mfma_f32_16x16x16bf16_1k)
    return __builtin_amdgcn_mfma_f32_16x16x16bf16_1k(a, b, c, 0, 0, 0);
#else
    asm("v_mfma_f32_16x16x16_bf16 %0, %1, %2, %0" : "+v"(c) : "v"(a), "v"(b));
    return c;
#endif
}

// Block = 256 threads = 4 waves. Wave w -> m = mg*4 + w; all waves share rows
// n0..n0+255 so the block's x-reads form 256B-aligned chunks per row (no line
// sharing across blocks). Grid = 16 m-groups x 64 row-groups = 1024 blocks.
// Per wave: codebook-hi frags + norms in LDS (9KB/m), codebook-lo frags in 32 VGPRs.
__global__ __launch_bounds__(256, 4) void pq_main(
    const float* __restrict__ embeds,
    const float* __restrict__ codebooks,
    unsigned char* __restrict__ outb,     // out buffer viewed as bytes (idx scratch)
    unsigned* __restrict__ flag_cnt,
    unsigned* __restrict__ flag_list,
    unsigned flag_cap)
{
    __shared__ short chi[4][KCODE * DSUB];   // 32KB: bf16 hi of codebook[m] (MFMA-frag order)
    __shared__ float cnorm[4][KCODE];        // 4KB: -0.5*||c||^2

    const int tid = threadIdx.x;
    const int w   = tid >> 6;
    const int l   = tid & 63;
    const int col = l & 15;       // x-row within 16-row tile (C col); code-within-tile at staging
    const int ds  = l >> 4;       // k-segment (dims ds*4..+4); C row-group (codes)
    const int mg  = blockIdx.x & 15;
    const int rg  = blockIdx.x >> 4;
    const int m   = mg * 4 + w;
    const int n0  = rg << 8;                 // 256 rows per block

    const float* cbm = codebooks + (size_t)m * (KCODE * DSUB);

    // ---- Stage: lane l owns A-frags for codes kt*16+col, dims ds*4..+4 ----
    s16x4 clo_r[16];                         // lo residual frags stay in registers
    s16x4* chw = (s16x4*)chi[w];
    #pragma unroll
    for (int kt = 0; kt < 16; ++kt) {
        const float4 cv = *(const float4*)(cbm + (kt * 16 + col) * DSUB + ds * 4);
        short h0 = f2bf(cv.x), h1 = f2bf(cv.y), h2 = f2bf(cv.z), h3 = f2bf(cv.w);
        chw[kt * 64 + col * 4 + ds] = (s16x4){h0, h1, h2, h3};
        clo_r[kt] = (s16x4){f2bf(cv.x - bf2f(h0)), f2bf(cv.y - bf2f(h1)),
                            f2bf(cv.z - bf2f(h2)), f2bf(cv.w - bf2f(h3))};
        float ss = fmaf(cv.x, cv.x, fmaf(cv.y, cv.y, fmaf(cv.z, cv.z, cv.w * cv.w)));
        ss += __shfl_xor(ss, 16);
        ss += __shfl_xor(ss, 32);
        if (ds == 0) cnorm[w][kt * 16 + col] = -0.5f * ss;
    }
    __syncthreads();

    const float* xp = embeds + (size_t)(n0 + col) * DIMS + m * DSUB + ds * 4;
    const s16x4* chv = (const s16x4*)chi[w] + col * 4 + ds;   // + kt*64
    const f32x4* hv  = (const f32x4*)cnorm[w] + ds;           // + kt*4

    float4 xv = *(const float4*)xp;

    #pragma unroll 1
    for (int t = 0; t < 16; ++t) {
        // B fragments: x hi/lo (4 dims of row n0 + t*16 + col)
        s16x4 bh, bl;
        {
            short h0 = f2bf(xv.x), h1 = f2bf(xv.y), h2 = f2bf(xv.z), h3 = f2bf(xv.w);
            bh = (s16x4){h0, h1, h2, h3};
            bl = (s16x4){f2bf(xv.x - bf2f(h0)), f2bf(xv.y - bf2f(h1)),
                         f2bf(xv.z - bf2f(h2)), f2bf(xv.w - bf2f(h3))};
        }
        if (t < 15) xv = *(const float4*)(xp + (size_t)(t + 1) * 16 * DIMS);

        float best = -3e38f, sec = -3e38f;
        int idx = 0;

        #pragma unroll
        for (int kt = 0; kt < 16; ++kt) {
            f32x4 acc = hv[kt * 4];            // -0.5||c||^2 for this lane's 4 codes
            s16x4 ah = chv[kt * 64];
            acc = mfma16(ah, bh, acc);         // ch·xh
            acc = mfma16(clo_r[kt], bh, acc);  // cl·xh
            acc = mfma16(ah, bl, acc);         // ch·xl
            #pragma unroll
            for (int r = 0; r < 4; ++r) {
                float s = acc[r];
                bool gt = s > best;
                idx  = gt ? (kt * 16 + ds * 4 + r) : idx;
                sec  = fmaxf(sec, fminf(s, best));
                best = fmaxf(best, s);
            }
        }

        // Combine the 4 code-partitions (xor 16, 32): all lanes of a col agree.
        #pragma unroll
        for (int msk = 16; msk <= 32; msk <<= 1) {
            float ob = __shfl_xor(best, msk);
            float os = __shfl_xor(sec,  msk);
            int   oi = __shfl_xor(idx,  msk);
            sec  = fmaxf(fmaxf(sec, os), fminf(best, ob));
            bool gt = ob > best;
            idx  = gt ? oi : idx;
            best = fmaxf(best, ob);
        }

        if (l < 16) {
            const int n = n0 + t * 16 + l;
            outb[(size_t)n * (DIMS * 4) + m] = (unsigned char)idx;
            if (best - sec < MARGIN) {
                unsigned p = atomicAdd(flag_cnt, 1u);
                if (p < flag_cap) flag_list[p] = (unsigned)(n * 64 + m);
            }
        }
    }
}

// One wave per flagged (n,m): exact f64 distances, first-min tie-break; fix idx byte.
__global__ __launch_bounds__(256) void pq_refine(
    const float* __restrict__ embeds,
    const float* __restrict__ codebooks,
    unsigned char* __restrict__ outb,
    const unsigned* __restrict__ flag_cnt,
    const unsigned* __restrict__ flag_list,
    unsigned flag_cap)
{
    unsigned cnt = *flag_cnt;
    if (cnt > flag_cap) cnt = flag_cap;
    const int l = threadIdx.x & 63;
    const unsigned wid = (blockIdx.x << 2) | (unsigned)(threadIdx.x >> 6);
    const unsigned nw  = gridDim.x << 2;

    for (unsigned i = wid; i < cnt; i += nw) {
        const unsigned e = flag_list[i];
        const int n = (int)(e >> 6), m = (int)(e & 63u);
        const float* xrow = embeds + (size_t)n * DIMS + m * DSUB;
        double xd[DSUB];
        #pragma unroll
        for (int dd = 0; dd < DSUB; ++dd) xd[dd] = (double)xrow[dd];
        const float* cbm = codebooks + (size_t)m * (KCODE * DSUB);

        double bd = 1e300;
        int bi = 0;
        #pragma unroll 1
        for (int cc = 0; cc < 4; ++cc) {
            const int c = l * 4 + cc;                 // lane-local ascending
            const float* cp = cbm + c * DSUB;
            double s = 0.0;
            #pragma unroll
            for (int dd = 0; dd < DSUB; ++dd) {
                double diff = xd[dd] - (double)cp[dd];
                s = fma(diff, diff, s);
            }
            if (s < bd) { bd = s; bi = c; }
        }
        #pragma unroll
        for (int msk = 1; msk <= 32; msk <<= 1) {
            double ob = __shfl_xor(bd, msk);
            int   oi  = __shfl_xor(bi, msk);
            if (ob < bd || (ob == bd && oi < bi)) { bd = ob; bi = oi; }
        }
        if (l == 0) outb[(size_t)n * (DIMS * 4) + m] = (unsigned char)bi;
    }
}

// Phase 2: idx bytes -> full output rows. Thread tid handles floats [tid*4, tid*4+4)
// of each row (= subspace m = tid>>2, segment seg = tid&3). 8 rows per block.
__global__ __launch_bounds__(256) void pq_gather(
    const float* __restrict__ codebooks,
    float* __restrict__ out)
{
    const unsigned char* outb = (const unsigned char*)out;
    const int tid = threadIdx.x;
    const int m   = tid >> 2;
    const int seg = tid & 3;
    const int n0  = blockIdx.x * 8;

    unsigned char ids[8];
    #pragma unroll
    for (int r = 0; r < 8; ++r)
        ids[r] = outb[(size_t)(n0 + r) * (DIMS * 4) + m];
    __syncthreads();   // all idx reads done before any thread overwrites row bytes

    #pragma unroll
    for (int r = 0; r < 8; ++r) {
        const float4 v = *(const float4*)(codebooks +
                          ((size_t)m * KCODE + ids[r]) * DSUB + seg * 4);
        *(float4*)(out + (size_t)(n0 + r) * DIMS + tid * 4) = v;
    }
}

extern "C" void kernel_launch(void* const* d_in, const int* in_sizes, int n_in,
                              void* d_out, int out_size, void* d_ws, size_t ws_size,
                              hipStream_t stream)
{
    const float* embeds    = (const float*)d_in[0];
    const float* codebooks = (const float*)d_in[1];
    float* out = (float*)d_out;

    unsigned* flag_cnt  = (unsigned*)d_ws;
    unsigned* flag_list = (unsigned*)d_ws + 4;   // 16B offset
    unsigned flag_cap = 0;
    if (ws_size >= 32) {
        size_t cap = (ws_size - 16) / sizeof(unsigned);
        flag_cap = (cap > 0x7FFFFFFFull) ? 0x7FFFFFFFu : (unsigned)cap;
    }

    hipMemsetAsync(d_ws, 0, 16, stream);

    pq_main<<<dim3(1024), dim3(256), 0, stream>>>(
        embeds, codebooks, (unsigned char*)d_out, flag_cnt, flag_list, flag_cap);

    pq_refine<<<dim3(512), dim3(256), 0, stream>>>(
        embeds, codebooks, (unsigned char*)d_out, flag_cnt, flag_list, flag_cap);

    pq_gather<<<dim3(2048), dim3(256), 0, stream>>>(codebooks, out);
}

// Round 5
// 153.030 us; speedup vs baseline: 2.7845x; 2.7845x over previous
//
#include <hip/hip_runtime.h>

// Product quantizer: N=16384, D=1024, M=64 subspaces, K=256 codes, d=16.
// Scores s = x·c - 0.5||c||^2 via split-bf16 MFMA (ch·xh + cl·xh + ch·xl, |err|~5e-4;
// argmax == argmin dist). Codebook hi/lo/norms all in LDS (NO per-thread arrays ->
// no spill). Top-2 gap < MARGIN -> LDS-batched flag list -> exact f64 refine.
// Block mapping groups all 64 m-blocks of a row-group on one XCD (bid%8 heuristic)
// so the 64B-per-4KB-row reads/writes of shared 128B lines stay in one L2.

#define NROWS  16384
#define DIMS   1024
#define MSUB   64
#define KCODE  256
#define DSUB   16
#define FLCAP  512

static constexpr float MARGIN = 0.03f;

typedef __attribute__((ext_vector_type(4))) short s16x4;
typedef __attribute__((ext_vector_type(4))) float f32x4;

static __device__ __forceinline__ short f2bf(float f) {
    unsigned u = __float_as_uint(f);
    u += 0x7fffu + ((u >> 16) & 1u);          // RNE to bf16
    return (short)(u >> 16);
}
static __device__ __forceinline__ float bf2f(short h) {
    return __uint_as_float(((unsigned)(unsigned short)h) << 16);
}

static __device__ __forceinline__ f32x4 mfma16(s16x4 a, s16x4 b, f32x4 c) {
#if __has_builtin(__builtin_amdgcn_mfma_f32_16x16x16bf16_1k)
    return __builtin_amdgcn_mfma_f32_16x16x16bf16_1k(a, b, c, 0, 0, 0);
#else
    asm("v_mfma_f32_16x16x16_bf16 %0, %1, %2, %0" : "+v"(c) : "v"(a), "v"(b));
    return c;
#endif
}

// Block = 256 threads = 4 waves, one m per block, 1024 rows per block (wave: 256 rows
// = 16 tiles of 16). Grid 1024. LDS 19.4KB -> up to 8 blocks/CU.
__global__ __launch_bounds__(256, 2) void pq_main(
    const float* __restrict__ embeds,
    const float* __restrict__ codebooks,
    float* __restrict__ out,
    unsigned* __restrict__ flag_cnt,
    unsigned* __restrict__ flag_list,
    unsigned flag_cap)
{
    __shared__ short chi[KCODE * DSUB];   // 8KB: bf16 hi of codebook[m], [code][dim]
    __shared__ short clo[KCODE * DSUB];   // 8KB: bf16 lo residual
    __shared__ float cnorm[KCODE];        // 1KB: -0.5*||c||^2
    __shared__ unsigned fl_buf[FLCAP];    // 2KB: block-local flag queue
    __shared__ unsigned fl_cnt, fl_base;

    const int tid = threadIdx.x;
    const int bid = blockIdx.x;
    const int m   = (bid >> 3) & 63;                  // subspace
    const int g   = (bid & 7) | ((bid >> 9) << 3);    // row-group; all m of a g share bid%8
    const float* cbm = codebooks + (size_t)m * (KCODE * DSUB);

    if (tid == 0) fl_cnt = 0;

    // ---- Stage codebook[m]: thread tid owns code tid (contiguous 16KB block read) ----
    {
        const float4* src = (const float4*)(cbm + tid * DSUB);
        float c[16];
        #pragma unroll
        for (int q = 0; q < 4; ++q) {
            float4 v = src[q];
            c[4*q+0] = v.x; c[4*q+1] = v.y; c[4*q+2] = v.z; c[4*q+3] = v.w;
        }
        float ss = 0.f;
        s16x4* chv = (s16x4*)chi + tid * 4;
        s16x4* clv = (s16x4*)clo + tid * 4;
        #pragma unroll
        for (int q = 0; q < 4; ++q) {
            short h0 = f2bf(c[4*q+0]), h1 = f2bf(c[4*q+1]);
            short h2 = f2bf(c[4*q+2]), h3 = f2bf(c[4*q+3]);
            chv[q] = (s16x4){h0, h1, h2, h3};
            clv[q] = (s16x4){f2bf(c[4*q+0] - bf2f(h0)), f2bf(c[4*q+1] - bf2f(h1)),
                             f2bf(c[4*q+2] - bf2f(h2)), f2bf(c[4*q+3] - bf2f(h3))};
            ss = fmaf(c[4*q+0], c[4*q+0], ss); ss = fmaf(c[4*q+1], c[4*q+1], ss);
            ss = fmaf(c[4*q+2], c[4*q+2], ss); ss = fmaf(c[4*q+3], c[4*q+3], ss);
        }
        cnorm[tid] = -0.5f * ss;
    }
    __syncthreads();

    const int w   = tid >> 6;
    const int l   = tid & 63;
    const int col = l & 15;       // embed-row within 16-row tile (MFMA B/C col)
    const int ds  = l >> 4;       // k-segment (dims ds*4..+4); C row-group (codes)
    const int n0  = (g << 10) + (w << 8);

    const float* xp = embeds + (size_t)(n0 + col) * DIMS + m * DSUB + ds * 4;
    float*       op = out    + (size_t)(n0 + col) * DIMS + m * DSUB + ds * 4;
    const s16x4* chv = (const s16x4*)chi + col * 4 + ds;   // + kt*64 per k-tile
    const s16x4* clv = (const s16x4*)clo + col * 4 + ds;
    const f32x4* hv  = (const f32x4*)cnorm + ds;           // + kt*4 per k-tile
    const int cb4 = ds * 4;

    float4 xv = *(const float4*)xp;

    #pragma unroll 1
    for (int t = 0; t < 16; ++t) {
        // B fragments: x hi/lo (4 dims of row n0+t*16+col)
        s16x4 bh, bl;
        {
            short h0 = f2bf(xv.x), h1 = f2bf(xv.y), h2 = f2bf(xv.z), h3 = f2bf(xv.w);
            bh = (s16x4){h0, h1, h2, h3};
            bl = (s16x4){f2bf(xv.x - bf2f(h0)), f2bf(xv.y - bf2f(h1)),
                         f2bf(xv.z - bf2f(h2)), f2bf(xv.w - bf2f(h3))};
        }
        if (t < 15) xv = *(const float4*)(xp + (size_t)(t + 1) * 16 * DIMS);

        float best = -3e38f, sec = -3e38f;
        int idx = 0;

        #pragma unroll
        for (int kt = 0; kt < 16; ++kt) {
            f32x4 acc = hv[kt * 4];            // -0.5||c||^2 for this lane's 4 codes
            s16x4 ah = chv[kt * 64];
            s16x4 al = clv[kt * 64];
            acc = mfma16(ah, bh, acc);         // ch·xh
            acc = mfma16(al, bh, acc);         // cl·xh
            acc = mfma16(ah, bl, acc);         // ch·xl
            #pragma unroll
            for (int r = 0; r < 4; ++r) {
                float s = acc[r];
                bool gt = s > best;
                idx  = gt ? (kt * 16 + cb4 + r) : idx;
                sec  = fmaxf(sec, fminf(s, best));
                best = fmaxf(best, s);
            }
        }

        // Combine the 4 code-partitions (xor 16, 32): all lanes of a col agree.
        #pragma unroll
        for (int msk = 16; msk <= 32; msk <<= 1) {
            float ob = __shfl_xor(best, msk);
            float os = __shfl_xor(sec,  msk);
            int   oi = __shfl_xor(idx,  msk);
            sec  = fmaxf(fmaxf(sec, os), fminf(best, ob));
            bool gt = ob > best;
            idx  = gt ? oi : idx;
            best = fmaxf(best, ob);
        }

        // Exact f32 codeword gather (L1-hot) + 64B-chunk store (same-XCD line sharing).
        const float4 cv = *(const float4*)(cbm + (size_t)idx * DSUB + cb4);
        *(float4*)(op + (size_t)t * 16 * DIMS) = cv;

        if (ds == 0 && best - sec < MARGIN) {
            unsigned ent = (unsigned)((n0 + t * 16 + col) * 64 + m);
            unsigned p = atomicAdd(&fl_cnt, 1u);          // LDS atomic (cheap)
            if (p < FLCAP) fl_buf[p] = ent;
            else {                                        // ~never: safe fallback
                unsigned q = atomicAdd(flag_cnt, 1u);
                if (q < flag_cap) flag_list[q] = ent;
            }
        }
    }

    // ---- One global atomic per block; coalesced flag flush ----
    __syncthreads();
    unsigned c = fl_cnt; if (c > FLCAP) c = FLCAP;
    if (tid == 0) fl_base = atomicAdd(flag_cnt, c);
    __syncthreads();
    const unsigned base = fl_base;
    for (unsigned i = tid; i < c; i += 256) {
        unsigned p = base + i;
        if (p < flag_cap) flag_list[p] = fl_buf[i];
    }
}

// One wave per flagged (n,m): exact f64 distances, first-min tie-break.
__global__ __launch_bounds__(256) void pq_refine(
    const float* __restrict__ embeds,
    const float* __restrict__ codebooks,
    float* __restrict__ out,
    const unsigned* __restrict__ flag_cnt,
    const unsigned* __restrict__ flag_list,
    unsigned flag_cap)
{
    unsigned cnt = *flag_cnt;
    if (cnt > flag_cap) cnt = flag_cap;
    const int l = threadIdx.x & 63;
    const unsigned wid = (blockIdx.x << 2) | (unsigned)(threadIdx.x >> 6);
    const unsigned nw  = gridDim.x << 2;

    for (unsigned i = wid; i < cnt; i += nw) {
        const unsigned e = flag_list[i];
        const int n = (int)(e >> 6), m = (int)(e & 63u);
        const float* xrow = embeds + (size_t)n * DIMS + m * DSUB;
        double xd[DSUB];
        #pragma unroll
        for (int dd = 0; dd < DSUB; ++dd) xd[dd] = (double)xrow[dd];
        const float* cbm = codebooks + (size_t)m * (KCODE * DSUB);

        double bd = 1e300;
        int bi = 0;
        #pragma unroll 1
        for (int cc = 0; cc < 4; ++cc) {
            const int c = l * 4 + cc;                 // lane-local ascending
            const float* cp = cbm + c * DSUB;
            double s = 0.0;
            #pragma unroll
            for (int dd = 0; dd < DSUB; ++dd) {
                double diff = xd[dd] - (double)cp[dd];
                s = fma(diff, diff, s);
            }
            if (s < bd) { bd = s; bi = c; }
        }
        #pragma unroll
        for (int msk = 1; msk <= 32; msk <<= 1) {
            double ob = __shfl_xor(bd, msk);
            int   oi  = __shfl_xor(bi, msk);
            if (ob < bd || (ob == bd && oi < bi)) { bd = ob; bi = oi; }
        }
        if (l < DSUB) out[(size_t)n * DIMS + m * DSUB + l] = cbm[bi * DSUB + l];
    }
}

extern "C" void kernel_launch(void* const* d_in, const int* in_sizes, int n_in,
                              void* d_out, int out_size, void* d_ws, size_t ws_size,
                              hipStream_t stream)
{
    const float* embeds    = (const float*)d_in[0];
    const float* codebooks = (const float*)d_in[1];
    float* out = (float*)d_out;

    unsigned* flag_cnt  = (unsigned*)d_ws;
    unsigned* flag_list = (unsigned*)d_ws + 4;   // 16B offset
    unsigned flag_cap = 0;
    if (ws_size >= 32) {
        size_t cap = (ws_size - 16) / sizeof(unsigned);
        flag_cap = (cap > 0x7FFFFFFFull) ? 0x7FFFFFFFu : (unsigned)cap;
    }

    hipMemsetAsync(d_ws, 0, 16, stream);

    pq_main<<<dim3(1024), dim3(256), 0, stream>>>(
        embeds, codebooks, out, flag_cnt, flag_list, flag_cap);

    pq_refine<<<dim3(512), dim3(256), 0, stream>>>(
        embeds, codebooks, out, flag_cnt, flag_list, flag_cap);
}